// Round 20
// baseline (3096.682 us; speedup 1.0000x reference)
//
#include <hip/hip_runtime.h>
#include <math.h>

constexpr int B   = 128;
constexpr int N   = 512;   // NNB + 2
constexpr int NNB = 510;
constexpr int D   = 128;
constexpr int FFH = 512;
constexpr int NL  = 3;

__device__ __forceinline__ float sigmoidf_(float x) { return 1.f / (1.f + expf(-x)); }

#define F4ADD(a, b) { (a).x += (b).x; (a).y += (b).y; (a).z += (b).z; (a).w += (b).w; }

// ---------------------------------------------------------------------------
// XLA f32 FastTanh — exact tie structure of the jax reference. DO NOT TOUCH.
// ---------------------------------------------------------------------------
__device__ __forceinline__ float xla_fast_tanh(float x) {
    if (fabsf(x) < 0.0004f) return x;
    const float C = 7.99881172180175781f;
    float xc = fminf(fmaxf(x, -C), C);
    float x2 = __fmul_rn(xc, xc);
    float num = -2.76076847742355e-16f;
    num = __builtin_fmaf(x2, num, 2.00018790482477e-13f);
    num = __builtin_fmaf(x2, num, -8.60467152213735e-11f);
    num = __builtin_fmaf(x2, num, 5.12229709037114e-08f);
    num = __builtin_fmaf(x2, num, 1.48572235717979e-05f);
    num = __builtin_fmaf(x2, num, 6.37261928875436e-04f);
    num = __builtin_fmaf(x2, num, 4.89352455891786e-03f);
    num = __fmul_rn(xc, num);
    float den = 1.19825839466702e-06f;
    den = __builtin_fmaf(x2, den, 1.18534705686654e-04f);
    den = __builtin_fmaf(x2, den, 2.26843463243900e-03f);
    den = __builtin_fmaf(x2, den, 4.89352518554385e-03f);
    return num / den;
}

// ---------------------------------------------------------------------------
// Build x (B,N,D) f32.
// ---------------------------------------------------------------------------
__global__ __launch_bounds__(128) void build_x_kernel(
    const float* __restrict__ xy, const float* __restrict__ load,
    const float* __restrict__ demand, const float* __restrict__ mask,
    const float* __restrict__ embW, const float* __restrict__ embb,
    const float* __restrict__ wload, const float* __restrict__ wdem,
    const float* __restrict__ Wqf, const float* __restrict__ Wql,
    float* __restrict__ x)
{
    __shared__ float fln[128];
    const int bn = blockIdx.x;
    const int b  = bn >> 9;
    const int n  = bn & 511;
    const int d  = threadIdx.x;
    float l = load[b];
    float load3 = (l == 0.f) ? 1.f : l;

    if (n >= 2) {
        const int j = n - 2;
        float m = mask[(size_t)b * N + n];
        float out = 0.f;
        if (!(m < 0.f)) {
            float x0 = xy[(size_t)bn * 2 + 0];
            float x1 = xy[(size_t)bn * 2 + 1];
            float fl = x0 * embW[d] + x1 * embW[D + d] + embb[d];
            float dm = demand[(size_t)b * NNB + j] / load3;
            dm = fminf(fmaxf(dm, 0.f), 1.f);
            out = fl + dm * wdem[d];
        }
        x[(size_t)bn * D + d] = out;
    } else {
        float x0 = xy[(size_t)bn * 2 + 0];
        float x1 = xy[(size_t)bn * 2 + 1];
        fln[d] = x0 * embW[d] + x1 * embW[D + d] + embb[d];
        __syncthreads();
        const float* W = (n == 0) ? Wqf : Wql;
        float acc = 0.f;
        #pragma unroll 8
        for (int e = 0; e < D; ++e) acc = fmaf(fln[e], W[(size_t)e * D + d], acc);
        x[(size_t)bn * D + d] = acc + load3 * wload[d];
    }
}

// ---------------------------------------------------------------------------
// Tiled f32 GEMM 64x128, BK=32, 256 thr, reg double-buffer (r17 core).
// __launch_bounds__(256,5): request 5 blocks/CU (VGPR cap ~102) for better
// latency hiding in the barrier-synced dbuf loop. Math unchanged (bit-exact).
// QKV mode: Wb != nullptr -> blockIdx.y in {0,1,2} selects (W,C); n0 = 0.
// Else n0 = blockIdx.y*128.  LNF=1: fused out = LN(resid+o)*g+be (Nc==128).
// ---------------------------------------------------------------------------
template<bool BIAS, bool RELU, int LNF>
__global__ __launch_bounds__(256, 5) void gemm_f32(
    const float* __restrict__ A,
    const float* W0, const float* Wb, const float* Wc,
    const float* __restrict__ bias,
    float* C0, float* Cb, float* Cc,
    const float* resid, const float* __restrict__ g, const float* __restrict__ be,
    int M, int K, int Nc)
{
    __shared__ float As[64][40];
    __shared__ float Ws[32][132];
    const float* W = W0;
    float* C = C0;
    int n0 = 0;
    if (Wb != nullptr) {
        if (blockIdx.y == 1)      { W = Wb; C = Cb; }
        else if (blockIdx.y == 2) { W = Wc; C = Cc; }
    } else {
        n0 = blockIdx.y * 128;
    }
    const int m0 = blockIdx.x * 64;
    const int tid = threadIdx.x;
    const int tc = tid & 31;
    const int tr = tid >> 5;

    const int ar0 = tid >> 3,          ac0 = (tid & 7) * 4;
    const int ar1 = (tid + 256) >> 3,  ac1 = ((tid + 256) & 7) * 4;
    int wr[4], wc[4];
    #pragma unroll
    for (int i = 0; i < 4; ++i) {
        int f = tid + i * 256;
        wr[i] = f >> 5; wc[i] = (f & 31) * 4;
    }

    float4 acc[8];
    #pragma unroll
    for (int r = 0; r < 8; ++r) acc[r] = make_float4(0.f, 0.f, 0.f, 0.f);

    {
        float4 a0 = *(const float4*)&A[(size_t)(m0 + ar0) * K + ac0];
        float4 a1 = *(const float4*)&A[(size_t)(m0 + ar1) * K + ac1];
        float4 w0 = *(const float4*)&W[(size_t)(0 + wr[0]) * Nc + n0 + wc[0]];
        float4 w1 = *(const float4*)&W[(size_t)(0 + wr[1]) * Nc + n0 + wc[1]];
        float4 w2 = *(const float4*)&W[(size_t)(0 + wr[2]) * Nc + n0 + wc[2]];
        float4 w3 = *(const float4*)&W[(size_t)(0 + wr[3]) * Nc + n0 + wc[3]];
        *(float4*)&As[ar0][ac0] = a0;
        *(float4*)&As[ar1][ac1] = a1;
        *(float4*)&Ws[wr[0]][wc[0]] = w0;
        *(float4*)&Ws[wr[1]][wc[1]] = w1;
        *(float4*)&Ws[wr[2]][wc[2]] = w2;
        *(float4*)&Ws[wr[3]][wc[3]] = w3;
    }
    __syncthreads();

    for (int kt = 0; kt < K; kt += 32) {
        const bool more = (kt + 32) < K;
        float4 na0, na1, nw0, nw1, nw2, nw3;
        if (more) {
            int kn = kt + 32;
            na0 = *(const float4*)&A[(size_t)(m0 + ar0) * K + kn + ac0];
            na1 = *(const float4*)&A[(size_t)(m0 + ar1) * K + kn + ac1];
            nw0 = *(const float4*)&W[(size_t)(kn + wr[0]) * Nc + n0 + wc[0]];
            nw1 = *(const float4*)&W[(size_t)(kn + wr[1]) * Nc + n0 + wc[1]];
            nw2 = *(const float4*)&W[(size_t)(kn + wr[2]) * Nc + n0 + wc[2]];
            nw3 = *(const float4*)&W[(size_t)(kn + wr[3]) * Nc + n0 + wc[3]];
        }
        #pragma unroll
        for (int kk = 0; kk < 32; kk += 4) {
            float4 w0 = *(float4*)&Ws[kk + 0][tc * 4];
            float4 w1 = *(float4*)&Ws[kk + 1][tc * 4];
            float4 w2 = *(float4*)&Ws[kk + 2][tc * 4];
            float4 w3 = *(float4*)&Ws[kk + 3][tc * 4];
            #pragma unroll
            for (int r = 0; r < 8; ++r) {
                float4 a4 = *(float4*)&As[tr * 8 + r][kk];
                acc[r].x = fmaf(a4.x, w0.x, acc[r].x); acc[r].x = fmaf(a4.y, w1.x, acc[r].x);
                acc[r].x = fmaf(a4.z, w2.x, acc[r].x); acc[r].x = fmaf(a4.w, w3.x, acc[r].x);
                acc[r].y = fmaf(a4.x, w0.y, acc[r].y); acc[r].y = fmaf(a4.y, w1.y, acc[r].y);
                acc[r].y = fmaf(a4.z, w2.y, acc[r].y); acc[r].y = fmaf(a4.w, w3.y, acc[r].y);
                acc[r].z = fmaf(a4.x, w0.z, acc[r].z); acc[r].z = fmaf(a4.y, w1.z, acc[r].z);
                acc[r].z = fmaf(a4.z, w2.z, acc[r].z); acc[r].z = fmaf(a4.w, w3.z, acc[r].z);
                acc[r].w = fmaf(a4.x, w0.w, acc[r].w); acc[r].w = fmaf(a4.y, w1.w, acc[r].w);
                acc[r].w = fmaf(a4.z, w2.w, acc[r].w); acc[r].w = fmaf(a4.w, w3.w, acc[r].w);
            }
        }
        if (more) {
            __syncthreads();
            *(float4*)&As[ar0][ac0] = na0;
            *(float4*)&As[ar1][ac1] = na1;
            *(float4*)&Ws[wr[0]][wc[0]] = nw0;
            *(float4*)&Ws[wr[1]][wc[1]] = nw1;
            *(float4*)&Ws[wr[2]][wc[2]] = nw2;
            *(float4*)&Ws[wr[3]][wc[3]] = nw3;
            __syncthreads();
        }
    }

    float4 bv = make_float4(0.f, 0.f, 0.f, 0.f);
    if (BIAS) bv = *(const float4*)&bias[n0 + tc * 4];
    if constexpr (LNF == 0) {
        #pragma unroll
        for (int r = 0; r < 8; ++r) {
            float4 o = acc[r];
            if (BIAS) { o.x += bv.x; o.y += bv.y; o.z += bv.z; o.w += bv.w; }
            if (RELU) {
                o.x = fmaxf(o.x, 0.f); o.y = fmaxf(o.y, 0.f);
                o.z = fmaxf(o.z, 0.f); o.w = fmaxf(o.w, 0.f);
            }
            *(float4*)&C[(size_t)(m0 + tr * 8 + r) * Nc + n0 + tc * 4] = o;
        }
    } else {
        float4 gv  = *(const float4*)&g[tc * 4];
        float4 bev = *(const float4*)&be[tc * 4];
        #pragma unroll
        for (int r = 0; r < 8; ++r) {
            float4 o = acc[r];
            o.x += bv.x; o.y += bv.y; o.z += bv.z; o.w += bv.w;
            size_t row = (size_t)(m0 + tr * 8 + r);
            float4 xv = *(const float4*)&resid[row * 128 + tc * 4];
            float y0 = xv.x + o.x, y1 = xv.y + o.y, y2 = xv.z + o.z, y3 = xv.w + o.w;
            float s = ((y0 + y1) + y2) + y3;
            #pragma unroll
            for (int mm = 16; mm > 0; mm >>= 1) s += __shfl_xor(s, mm);
            float mean = s * (1.f / 128.f);
            float d0_ = y0 - mean, d1_ = y1 - mean, d2_ = y2 - mean, d3_ = y3 - mean;
            float ss = ((d0_ * d0_ + d1_ * d1_) + d2_ * d2_) + d3_ * d3_;
            #pragma unroll
            for (int mm = 16; mm > 0; mm >>= 1) ss += __shfl_xor(ss, mm);
            float rs = rsqrtf(ss * (1.f / 128.f) + 1e-5f);
            float4 ov;
            ov.x = d0_ * rs * gv.x + bev.x;
            ov.y = d1_ * rs * gv.y + bev.y;
            ov.z = d2_ * rs * gv.z + bev.z;
            ov.w = d3_ * rs * gv.w + bev.w;
            *(float4*)&C[row * 128 + tc * 4] = ov;
        }
    }
}

// ---------------------------------------------------------------------------
// Column-max of k over s (axis=1), then ekv = [ek*v ; ek] (B,N,256).
// ---------------------------------------------------------------------------
__global__ __launch_bounds__(128) void colmax_part(
    const float* __restrict__ k, float* __restrict__ part)
{
    int b = blockIdx.x >> 3, c = blockIdx.x & 7, d = threadIdx.x;
    const float* kp = k + ((size_t)b * N + c * 64) * D + d;
    float m = -3.4e38f;
    #pragma unroll 8
    for (int s = 0; s < 64; ++s) m = fmaxf(m, kp[(size_t)s * D]);
    part[(size_t)blockIdx.x * D + d] = m;
}

__global__ __launch_bounds__(128) void ekv_build(
    const float* __restrict__ k, const float* __restrict__ v,
    const float* __restrict__ part, float* __restrict__ ekv)
{
    int b = blockIdx.x >> 3, c = blockIdx.x & 7, d = threadIdx.x;
    float m = -3.4e38f;
    #pragma unroll
    for (int j = 0; j < 8; ++j) m = fmaxf(m, part[((size_t)b * 8 + j) * D + d]);
    for (int s = 0; s < 64; ++s) {
        int sg = c * 64 + s;
        size_t off = ((size_t)b * N + sg) * D + d;
        float ek = expf(k[off] - m);
        size_t o2 = ((size_t)b * N + sg) * 256;
        ekv[o2 + d]       = ek * v[off];
        ekv[o2 + 128 + d] = ek;
    }
}

// ---------------------------------------------------------------------------
// Fused AAFM attention + LN1 — r14 structure (single prefetch, acc[16]
// split-s, all-wave epilogue). Unchanged.
// ---------------------------------------------------------------------------
__global__ __launch_bounds__(256) void attn_kernel(
    const float* __restrict__ pdist, const float* __restrict__ mask,
    const float* __restrict__ ekv, const float* __restrict__ q,
    const float* xres, const float* __restrict__ g, const float* __restrict__ be,
    const int* __restrict__ nnum, const float* __restrict__ alphaAttn, int layer,
    float* outp)
{
    __shared__ float ew[16][516];
    __shared__ float red16[16][16];
    __shared__ float rmax[16];
    const int d0  = blockIdx.x;          // XCD-aware bijective swizzle
    const int xcd = d0 & 7;
    const int idx = d0 >> 3;
    const int tl  = idx & 31;
    const int b   = (idx >> 5) * 8 + xcd;
    const int t0  = tl * 16;
    const int tid = threadIdx.x;
    const float la = -log2f((float)nnum[b]) * alphaAttn[layer];
    const float* pd = pdist + ((size_t)b * N + t0) * N;
    const float* mk = mask + (size_t)b * N;

    #pragma unroll
    for (int i = 0; i < 8; ++i) {
        int f = tid + i * 256;
        int r = f >> 7, s4 = (f & 127) * 4;
        float4 p = *(const float4*)&pd[(size_t)r * N + s4];
        float4 m = *(const float4*)&mk[s4];
        float4 w;
        w.x = fmaf(la, p.x, m.x); w.y = fmaf(la, p.y, m.y);
        w.z = fmaf(la, p.z, m.z); w.w = fmaf(la, p.w, m.w);
        *(float4*)&ew[r][s4] = w;
    }
    __syncthreads();
    {   // row max: stride-16 interleave -> <=2-way banks
        int r = tid >> 4, j0 = tid & 15;
        float m = -3.4e38f;
        #pragma unroll 8
        for (int j = 0; j < 32; ++j) m = fmaxf(m, ew[r][j0 + 16 * j]);
        red16[r][j0] = m;
    }
    __syncthreads();
    if (tid < 16) {
        float m = red16[tid][0];
        #pragma unroll
        for (int j = 1; j < 16; ++j) m = fmaxf(m, red16[tid][j]);
        rmax[tid] = m;
    }
    __syncthreads();
    #pragma unroll
    for (int i = 0; i < 8; ++i) {
        int f = tid + i * 256;
        int r = f >> 7, s4 = (f & 127) * 4;
        float m = rmax[r];
        float4 w = *(float4*)&ew[r][s4];
        w.x = expf(w.x - m); w.y = expf(w.y - m);
        w.z = expf(w.z - m); w.w = expf(w.w - m);
        *(float4*)&ew[r][s4] = w;
    }
    __syncthreads();

    // ----- split-s partial [num|den] -----
    const int lane = tid & 63;
    const int wv   = tid >> 6;
    const int c4   = lane * 4;
    float4 acc[16];
    #pragma unroll
    for (int r = 0; r < 16; ++r) acc[r] = make_float4(0.f, 0.f, 0.f, 0.f);
    const float* ep = ekv + (size_t)b * N * 256 + c4;
    const int sb = wv * 128;
    float4 e0 = *(const float4*)&ep[(size_t)(sb + 0) * 256];
    float4 e1 = *(const float4*)&ep[(size_t)(sb + 1) * 256];
    float4 e2 = *(const float4*)&ep[(size_t)(sb + 2) * 256];
    float4 e3 = *(const float4*)&ep[(size_t)(sb + 3) * 256];
    for (int it = 0; it < 32; ++it) {
        const int s = sb + it * 4;
        float4 f0 = e0, f1 = e1, f2 = e2, f3 = e3;
        int sn = (it < 31) ? (s + 4) : s;       // uniform clamp
        e0 = *(const float4*)&ep[(size_t)(sn + 0) * 256];
        e1 = *(const float4*)&ep[(size_t)(sn + 1) * 256];
        e2 = *(const float4*)&ep[(size_t)(sn + 2) * 256];
        e3 = *(const float4*)&ep[(size_t)(sn + 3) * 256];
        #pragma unroll
        for (int r = 0; r < 16; ++r) {
            float4 a = *(float4*)&ew[r][s];
            acc[r].x = fmaf(a.x, f0.x, acc[r].x); acc[r].x = fmaf(a.y, f1.x, acc[r].x);
            acc[r].x = fmaf(a.z, f2.x, acc[r].x); acc[r].x = fmaf(a.w, f3.x, acc[r].x);
            acc[r].y = fmaf(a.x, f0.y, acc[r].y); acc[r].y = fmaf(a.y, f1.y, acc[r].y);
            acc[r].y = fmaf(a.z, f2.y, acc[r].y); acc[r].y = fmaf(a.w, f3.y, acc[r].y);
            acc[r].z = fmaf(a.x, f0.z, acc[r].z); acc[r].z = fmaf(a.y, f1.z, acc[r].z);
            acc[r].z = fmaf(a.z, f2.z, acc[r].z); acc[r].z = fmaf(a.w, f3.z, acc[r].z);
            acc[r].w = fmaf(a.x, f0.w, acc[r].w); acc[r].w = fmaf(a.y, f1.w, acc[r].w);
            acc[r].w = fmaf(a.z, f2.w, acc[r].w); acc[r].w = fmaf(a.w, f3.w, acc[r].w);
        }
    }

    // ----- cross-wave reduction: (w0 + w1) + (w2 + w3) -----
    float* red = &ew[0][0];
    __syncthreads();
    if (wv == 1) {
        #pragma unroll
        for (int r = 0; r < 16; ++r) *(float4*)&red[r * 256 + c4] = acc[r];
    }
    if (wv == 3) {
        #pragma unroll
        for (int r = 0; r < 16; ++r) *(float4*)&red[4096 + r * 256 + c4] = acc[r];
    }
    __syncthreads();
    if (wv == 0) {
        #pragma unroll
        for (int r = 0; r < 16; ++r) { float4 t = *(float4*)&red[r * 256 + c4]; F4ADD(acc[r], t); }
    }
    if (wv == 2) {
        #pragma unroll
        for (int r = 0; r < 16; ++r) { float4 t = *(float4*)&red[4096 + r * 256 + c4]; F4ADD(acc[r], t); }
    }
    __syncthreads();
    if (wv == 2) {
        #pragma unroll
        for (int r = 0; r < 16; ++r) *(float4*)&red[r * 256 + c4] = acc[r];
    }
    __syncthreads();
    if (wv == 0) {
        #pragma unroll
        for (int r = 0; r < 16; ++r) {
            float4 t = *(float4*)&red[r * 256 + c4];
            F4ADD(acc[r], t);
            *(float4*)&red[r * 256 + c4] = acc[r];   // publish final
        }
    }
    __syncthreads();

    // ----- all-wave epilogue: wave wv owns rows wv*4..wv*4+3 -----
    if (lane < 32) {
        const int c = lane * 4;
        #pragma unroll
        for (int i = 0; i < 4; ++i) {
            int row = wv * 4 + i;
            float4 nu = *(float4*)&red[row * 256 + c];
            float4 de = *(float4*)&red[row * 256 + 128 + c];
            size_t off = ((size_t)b * N + t0 + row) * D + c;
            float4 qq = *(const float4*)&q[off];
            float4 av;
            av.x = sigmoidf_(qq.x) * nu.x / de.x;
            av.y = sigmoidf_(qq.y) * nu.y / de.y;
            av.z = sigmoidf_(qq.z) * nu.z / de.z;
            av.w = sigmoidf_(qq.w) * nu.w / de.w;
            float4 xv = *(const float4*)&xres[off];
            float y0 = xv.x + av.x, y1 = xv.y + av.y;
            float y2 = xv.z + av.z, y3 = xv.w + av.w;
            float s = ((y0 + y1) + y2) + y3;
            #pragma unroll
            for (int mm = 16; mm > 0; mm >>= 1) s += __shfl_xor(s, mm);
            float mean = s * (1.f / 128.f);
            float d0_ = y0 - mean, d1_ = y1 - mean, d2_ = y2 - mean, d3_ = y3 - mean;
            float ss = ((d0_ * d0_ + d1_ * d1_) + d2_ * d2_) + d3_ * d3_;
            #pragma unroll
            for (int mm = 16; mm > 0; mm >>= 1) ss += __shfl_xor(ss, mm);
            float rs = rsqrtf(ss * (1.f / 128.f) + 1e-5f);
            float4 ov;
            ov.x = d0_ * rs * g[c]     + be[c];
            ov.y = d1_ * rs * g[c + 1] + be[c + 1];
            ov.z = d2_ * rs * g[c + 2] + be[c + 2];
            ov.w = d3_ * rs * g[c + 3] + be[c + 3];
            *(float4*)&outp[off] = ov;
        }
    }
}

// ---------------------------------------------------------------------------
// Final head (r8-validated): f64 score dot, XLA-f32 FastTanh, f32 softmax,
// first-occurrence argmax over p.
// ---------------------------------------------------------------------------
__global__ __launch_bounds__(512) void k_final(
    const float* __restrict__ x, const float* __restrict__ pdist,
    const float* __restrict__ mask, const int* __restrict__ nnum,
    const int* __restrict__ nidx, const float* __restrict__ aCom,
    float* __restrict__ out)
{
    __shared__ float  sc[512];
    __shared__ float  ee[512];
    __shared__ double qo[128];
    int b = blockIdx.x, tid = threadIdx.x;
    const float* xb = x + (size_t)b * N * D;
    if (tid < 128) qo[tid] = (double)xb[tid] + (double)xb[128 + tid];
    __syncthreads();
    if (tid < NNB) {
        const float* xr = xb + (size_t)(2 + tid) * 128;
        double s = 0.0;
        for (int dd = 0; dd < 128; ++dd) s += qo[dd] * (double)xr[dd];
        double lg = -log2((double)nnum[b]);
        s = s / 11.313708498984761
          + (double)aCom[0] * lg * (double)pdist[((size_t)b * 512 + 1) * 512 + 2 + tid];
        float t = xla_fast_tanh((float)s);
        sc[tid] = __fadd_rn(__fmul_rn(10.0f, t),
                            mask[(size_t)b * 512 + 2 + tid]);
    }
    __syncthreads();
    if (tid == 0) {
        float m = -3.4e38f;
        for (int n2 = 0; n2 < NNB; ++n2) m = fmaxf(m, sc[n2]);
        float S = 0.f;
        for (int n2 = 0; n2 < NNB; ++n2) {
            float e = expf(__fadd_rn(sc[n2], -m));
            ee[n2] = e;
            S = __fadd_rn(S, e);
        }
        float bestp = -1.f; int sel = 0;
        for (int n2 = 0; n2 < NNB; ++n2) {
            float p = ee[n2] / S;
            if (p > bestp) { bestp = p; sel = n2; }
        }
        out[b]     = (float)nidx[(size_t)b * NNB + sel];
        out[B + b] = bestp;
    }
}

// ---------------------------------------------------------------------------
extern "C" void kernel_launch(void* const* d_in, const int* in_sizes, int n_in,
                              void* d_out, int out_size, void* d_ws, size_t ws_size,
                              hipStream_t stream)
{
    const float* xy     = (const float*)d_in[0];
    const float* load   = (const float*)d_in[1];
    const float* demand = (const float*)d_in[2];
    const float* mask   = (const float*)d_in[3];
    const float* pdist  = (const float*)d_in[4];
    const int*   nnum   = (const int*)d_in[5];
    const int*   nidx   = (const int*)d_in[6];
    const float* embW   = (const float*)d_in[7];
    const float* embb   = (const float*)d_in[8];
    const float* wload  = (const float*)d_in[9];
    const float* wdem   = (const float*)d_in[10];
    const float* Wqf    = (const float*)d_in[11];
    const float* Wql    = (const float*)d_in[12];
    const float* aCom   = (const float*)d_in[13];
    const float* Wq     = (const float*)d_in[14];
    const float* Wk     = (const float*)d_in[15];
    const float* Wv     = (const float*)d_in[16];
    const float* aAttn  = (const float*)d_in[17];
    const float* ln1g   = (const float*)d_in[18];
    const float* ln1b   = (const float*)d_in[19];
    const float* ln2g   = (const float*)d_in[20];
    const float* ln2b   = (const float*)d_in[21];
    const float* fW1    = (const float*)d_in[22];
    const float* fb1    = (const float*)d_in[23];
    const float* fW2    = (const float*)d_in[24];
    const float* fb2    = (const float*)d_in[25];
    float* out = (float*)d_out;

    // Workspace: 6*SZ + part (192 MB + 0.5 MB; ws >= 224 MiB per r6 sentinel).
    float* ws = (float*)d_ws;
    const size_t SZ = (size_t)B * N * D;      // 8388608 floats
    float* xbuf  = ws;                        // slot 0 (residual stream)
    float* qbuf  = ws + SZ;                   // slot 1
    float* kbuf  = ws + 2 * SZ;               // slot 2 (raw k; free post-ekv)
    float* vbuf  = ws + 3 * SZ;               // slot 3 (free post-ekv)
    float* ekv   = ws + 4 * SZ;               // slots 4-5 (free post-attn)
    float* part  = ws + 6 * SZ;               // 1024*128 floats (0.5 MB)
    float* bigh  = kbuf;                      // ff hidden full-M: slots 2-5

    build_x_kernel<<<B * N, 128, 0, stream>>>(xy, load, demand, mask, embW, embb,
                                              wload, wdem, Wqf, Wql, xbuf);
    const int M = B * N;                      // 65536
    for (int l = 0; l < NL; ++l) {
        // fused QKV: grid (M/64, 3)
        gemm_f32<false, false, 0><<<dim3(M / 64, 3), 256, 0, stream>>>(
            xbuf, Wq + (size_t)l * D * D, Wk + (size_t)l * D * D, Wv + (size_t)l * D * D,
            nullptr, qbuf, kbuf, vbuf, nullptr, nullptr, nullptr, M, D, D);
        colmax_part<<<B * 8, 128, 0, stream>>>(kbuf, part);
        ekv_build<<<B * 8, 128, 0, stream>>>(kbuf, vbuf, part, ekv);
        // attention + fused LN1 (writes xbuf in place)
        attn_kernel<<<B * 32, 256, 0, stream>>>(
            pdist, mask, ekv, qbuf, xbuf, ln1g + l * D, ln1b + l * D,
            nnum, aAttn, l, xbuf);
        // FF at full M (bigh spans slots 2-5)
        gemm_f32<true, true, 0><<<dim3(M / 64, FFH / 128), 256, 0, stream>>>(
            xbuf, fW1 + (size_t)l * D * FFH, nullptr, nullptr, fb1 + l * FFH,
            bigh, nullptr, nullptr, nullptr, nullptr, nullptr, M, D, FFH);
        // FF2 + fused LN2 (writes xbuf in place, resid = xbuf)
        gemm_f32<true, false, 1><<<dim3(M / 64, 1), 256, 0, stream>>>(
            bigh, fW2 + (size_t)l * FFH * D, nullptr, nullptr, fb2 + l * D,
            xbuf, nullptr, nullptr, xbuf, ln2g + l * D, ln2b + l * D, M, FFH, D);
    }
    k_final<<<B, 512, 0, stream>>>(xbuf, pdist, mask, nnum, nidx, aCom, out);
}

// Round 21
// 1820.246 us; speedup vs baseline: 1.7012x; 1.7012x over previous
//
#include <hip/hip_runtime.h>
#include <math.h>

constexpr int B   = 128;
constexpr int N   = 512;   // NNB + 2
constexpr int NNB = 510;
constexpr int D   = 128;
constexpr int FFH = 512;
constexpr int NL  = 3;

__device__ __forceinline__ float sigmoidf_(float x) { return 1.f / (1.f + expf(-x)); }

#define F4ADD(a, b) { (a).x += (b).x; (a).y += (b).y; (a).z += (b).z; (a).w += (b).w; }

// ---------------------------------------------------------------------------
// XLA f32 FastTanh — exact tie structure of the jax reference. DO NOT TOUCH.
// ---------------------------------------------------------------------------
__device__ __forceinline__ float xla_fast_tanh(float x) {
    if (fabsf(x) < 0.0004f) return x;
    const float C = 7.99881172180175781f;
    float xc = fminf(fmaxf(x, -C), C);
    float x2 = __fmul_rn(xc, xc);
    float num = -2.76076847742355e-16f;
    num = __builtin_fmaf(x2, num, 2.00018790482477e-13f);
    num = __builtin_fmaf(x2, num, -8.60467152213735e-11f);
    num = __builtin_fmaf(x2, num, 5.12229709037114e-08f);
    num = __builtin_fmaf(x2, num, 1.48572235717979e-05f);
    num = __builtin_fmaf(x2, num, 6.37261928875436e-04f);
    num = __builtin_fmaf(x2, num, 4.89352455891786e-03f);
    num = __fmul_rn(xc, num);
    float den = 1.19825839466702e-06f;
    den = __builtin_fmaf(x2, den, 1.18534705686654e-04f);
    den = __builtin_fmaf(x2, den, 2.26843463243900e-03f);
    den = __builtin_fmaf(x2, den, 4.89352518554385e-03f);
    return num / den;
}

// ---------------------------------------------------------------------------
// Build x (B,N,D) f32.
// ---------------------------------------------------------------------------
__global__ __launch_bounds__(128) void build_x_kernel(
    const float* __restrict__ xy, const float* __restrict__ load,
    const float* __restrict__ demand, const float* __restrict__ mask,
    const float* __restrict__ embW, const float* __restrict__ embb,
    const float* __restrict__ wload, const float* __restrict__ wdem,
    const float* __restrict__ Wqf, const float* __restrict__ Wql,
    float* __restrict__ x)
{
    __shared__ float fln[128];
    const int bn = blockIdx.x;
    const int b  = bn >> 9;
    const int n  = bn & 511;
    const int d  = threadIdx.x;
    float l = load[b];
    float load3 = (l == 0.f) ? 1.f : l;

    if (n >= 2) {
        const int j = n - 2;
        float m = mask[(size_t)b * N + n];
        float out = 0.f;
        if (!(m < 0.f)) {
            float x0 = xy[(size_t)bn * 2 + 0];
            float x1 = xy[(size_t)bn * 2 + 1];
            float fl = x0 * embW[d] + x1 * embW[D + d] + embb[d];
            float dm = demand[(size_t)b * NNB + j] / load3;
            dm = fminf(fmaxf(dm, 0.f), 1.f);
            out = fl + dm * wdem[d];
        }
        x[(size_t)bn * D + d] = out;
    } else {
        float x0 = xy[(size_t)bn * 2 + 0];
        float x1 = xy[(size_t)bn * 2 + 1];
        fln[d] = x0 * embW[d] + x1 * embW[D + d] + embb[d];
        __syncthreads();
        const float* W = (n == 0) ? Wqf : Wql;
        float acc = 0.f;
        #pragma unroll 8
        for (int e = 0; e < D; ++e) acc = fmaf(fln[e], W[(size_t)e * D + d], acc);
        x[(size_t)bn * D + d] = acc + load3 * wload[d];
    }
}

// ---------------------------------------------------------------------------
// Tiled f32 GEMM 64x128, BK=32, 256 thr, reg double-buffer (r17 core).
// NO min-waves hint: r20 proved __launch_bounds__(256,5) forces the allocator
// under the 64-VGPR occupancy quantum -> catastrophic spills (~1 GB/dispatch).
// QKV mode: Wb != nullptr -> blockIdx.y in {0,1,2} selects (W,C); n0 = 0.
// Else n0 = blockIdx.y*128.  LNF=1: fused out = LN(resid+o)*g+be (Nc==128).
// ---------------------------------------------------------------------------
template<bool BIAS, bool RELU, int LNF>
__global__ __launch_bounds__(256) void gemm_f32(
    const float* __restrict__ A,
    const float* W0, const float* Wb, const float* Wc,
    const float* __restrict__ bias,
    float* C0, float* Cb, float* Cc,
    const float* resid, const float* __restrict__ g, const float* __restrict__ be,
    int M, int K, int Nc)
{
    __shared__ float As[64][40];
    __shared__ float Ws[32][132];
    const float* W = W0;
    float* C = C0;
    int n0 = 0;
    if (Wb != nullptr) {
        if (blockIdx.y == 1)      { W = Wb; C = Cb; }
        else if (blockIdx.y == 2) { W = Wc; C = Cc; }
    } else {
        n0 = blockIdx.y * 128;
    }
    const int m0 = blockIdx.x * 64;
    const int tid = threadIdx.x;
    const int tc = tid & 31;
    const int tr = tid >> 5;

    const int ar0 = tid >> 3,          ac0 = (tid & 7) * 4;
    const int ar1 = (tid + 256) >> 3,  ac1 = ((tid + 256) & 7) * 4;
    int wr[4], wc[4];
    #pragma unroll
    for (int i = 0; i < 4; ++i) {
        int f = tid + i * 256;
        wr[i] = f >> 5; wc[i] = (f & 31) * 4;
    }

    float4 acc[8];
    #pragma unroll
    for (int r = 0; r < 8; ++r) acc[r] = make_float4(0.f, 0.f, 0.f, 0.f);

    {
        float4 a0 = *(const float4*)&A[(size_t)(m0 + ar0) * K + ac0];
        float4 a1 = *(const float4*)&A[(size_t)(m0 + ar1) * K + ac1];
        float4 w0 = *(const float4*)&W[(size_t)(0 + wr[0]) * Nc + n0 + wc[0]];
        float4 w1 = *(const float4*)&W[(size_t)(0 + wr[1]) * Nc + n0 + wc[1]];
        float4 w2 = *(const float4*)&W[(size_t)(0 + wr[2]) * Nc + n0 + wc[2]];
        float4 w3 = *(const float4*)&W[(size_t)(0 + wr[3]) * Nc + n0 + wc[3]];
        *(float4*)&As[ar0][ac0] = a0;
        *(float4*)&As[ar1][ac1] = a1;
        *(float4*)&Ws[wr[0]][wc[0]] = w0;
        *(float4*)&Ws[wr[1]][wc[1]] = w1;
        *(float4*)&Ws[wr[2]][wc[2]] = w2;
        *(float4*)&Ws[wr[3]][wc[3]] = w3;
    }
    __syncthreads();

    for (int kt = 0; kt < K; kt += 32) {
        const bool more = (kt + 32) < K;
        float4 na0, na1, nw0, nw1, nw2, nw3;
        if (more) {
            int kn = kt + 32;
            na0 = *(const float4*)&A[(size_t)(m0 + ar0) * K + kn + ac0];
            na1 = *(const float4*)&A[(size_t)(m0 + ar1) * K + kn + ac1];
            nw0 = *(const float4*)&W[(size_t)(kn + wr[0]) * Nc + n0 + wc[0]];
            nw1 = *(const float4*)&W[(size_t)(kn + wr[1]) * Nc + n0 + wc[1]];
            nw2 = *(const float4*)&W[(size_t)(kn + wr[2]) * Nc + n0 + wc[2]];
            nw3 = *(const float4*)&W[(size_t)(kn + wr[3]) * Nc + n0 + wc[3]];
        }
        #pragma unroll
        for (int kk = 0; kk < 32; kk += 4) {
            float4 w0 = *(float4*)&Ws[kk + 0][tc * 4];
            float4 w1 = *(float4*)&Ws[kk + 1][tc * 4];
            float4 w2 = *(float4*)&Ws[kk + 2][tc * 4];
            float4 w3 = *(float4*)&Ws[kk + 3][tc * 4];
            #pragma unroll
            for (int r = 0; r < 8; ++r) {
                float4 a4 = *(float4*)&As[tr * 8 + r][kk];
                acc[r].x = fmaf(a4.x, w0.x, acc[r].x); acc[r].x = fmaf(a4.y, w1.x, acc[r].x);
                acc[r].x = fmaf(a4.z, w2.x, acc[r].x); acc[r].x = fmaf(a4.w, w3.x, acc[r].x);
                acc[r].y = fmaf(a4.x, w0.y, acc[r].y); acc[r].y = fmaf(a4.y, w1.y, acc[r].y);
                acc[r].y = fmaf(a4.z, w2.y, acc[r].y); acc[r].y = fmaf(a4.w, w3.y, acc[r].y);
                acc[r].z = fmaf(a4.x, w0.z, acc[r].z); acc[r].z = fmaf(a4.y, w1.z, acc[r].z);
                acc[r].z = fmaf(a4.z, w2.z, acc[r].z); acc[r].z = fmaf(a4.w, w3.z, acc[r].z);
                acc[r].w = fmaf(a4.x, w0.w, acc[r].w); acc[r].w = fmaf(a4.y, w1.w, acc[r].w);
                acc[r].w = fmaf(a4.z, w2.w, acc[r].w); acc[r].w = fmaf(a4.w, w3.w, acc[r].w);
            }
        }
        if (more) {
            __syncthreads();
            *(float4*)&As[ar0][ac0] = na0;
            *(float4*)&As[ar1][ac1] = na1;
            *(float4*)&Ws[wr[0]][wc[0]] = nw0;
            *(float4*)&Ws[wr[1]][wc[1]] = nw1;
            *(float4*)&Ws[wr[2]][wc[2]] = nw2;
            *(float4*)&Ws[wr[3]][wc[3]] = nw3;
            __syncthreads();
        }
    }

    float4 bv = make_float4(0.f, 0.f, 0.f, 0.f);
    if (BIAS) bv = *(const float4*)&bias[n0 + tc * 4];
    if constexpr (LNF == 0) {
        #pragma unroll
        for (int r = 0; r < 8; ++r) {
            float4 o = acc[r];
            if (BIAS) { o.x += bv.x; o.y += bv.y; o.z += bv.z; o.w += bv.w; }
            if (RELU) {
                o.x = fmaxf(o.x, 0.f); o.y = fmaxf(o.y, 0.f);
                o.z = fmaxf(o.z, 0.f); o.w = fmaxf(o.w, 0.f);
            }
            *(float4*)&C[(size_t)(m0 + tr * 8 + r) * Nc + n0 + tc * 4] = o;
        }
    } else {
        float4 gv  = *(const float4*)&g[tc * 4];
        float4 bev = *(const float4*)&be[tc * 4];
        #pragma unroll
        for (int r = 0; r < 8; ++r) {
            float4 o = acc[r];
            o.x += bv.x; o.y += bv.y; o.z += bv.z; o.w += bv.w;
            size_t row = (size_t)(m0 + tr * 8 + r);
            float4 xv = *(const float4*)&resid[row * 128 + tc * 4];
            float y0 = xv.x + o.x, y1 = xv.y + o.y, y2 = xv.z + o.z, y3 = xv.w + o.w;
            float s = ((y0 + y1) + y2) + y3;
            #pragma unroll
            for (int mm = 16; mm > 0; mm >>= 1) s += __shfl_xor(s, mm);
            float mean = s * (1.f / 128.f);
            float d0_ = y0 - mean, d1_ = y1 - mean, d2_ = y2 - mean, d3_ = y3 - mean;
            float ss = ((d0_ * d0_ + d1_ * d1_) + d2_ * d2_) + d3_ * d3_;
            #pragma unroll
            for (int mm = 16; mm > 0; mm >>= 1) ss += __shfl_xor(ss, mm);
            float rs = rsqrtf(ss * (1.f / 128.f) + 1e-5f);
            float4 ov;
            ov.x = d0_ * rs * gv.x + bev.x;
            ov.y = d1_ * rs * gv.y + bev.y;
            ov.z = d2_ * rs * gv.z + bev.z;
            ov.w = d3_ * rs * gv.w + bev.w;
            *(float4*)&C[row * 128 + tc * 4] = ov;
        }
    }
}

// ---------------------------------------------------------------------------
// Column-max of k over s (axis=1), then ekv = [ek*v ; ek] (B,N,256).
// ---------------------------------------------------------------------------
__global__ __launch_bounds__(128) void colmax_part(
    const float* __restrict__ k, float* __restrict__ part)
{
    int b = blockIdx.x >> 3, c = blockIdx.x & 7, d = threadIdx.x;
    const float* kp = k + ((size_t)b * N + c * 64) * D + d;
    float m = -3.4e38f;
    #pragma unroll 8
    for (int s = 0; s < 64; ++s) m = fmaxf(m, kp[(size_t)s * D]);
    part[(size_t)blockIdx.x * D + d] = m;
}

__global__ __launch_bounds__(128) void ekv_build(
    const float* __restrict__ k, const float* __restrict__ v,
    const float* __restrict__ part, float* __restrict__ ekv)
{
    int b = blockIdx.x >> 3, c = blockIdx.x & 7, d = threadIdx.x;
    float m = -3.4e38f;
    #pragma unroll
    for (int j = 0; j < 8; ++j) m = fmaxf(m, part[((size_t)b * 8 + j) * D + d]);
    for (int s = 0; s < 64; ++s) {
        int sg = c * 64 + s;
        size_t off = ((size_t)b * N + sg) * D + d;
        float ek = expf(k[off] - m);
        size_t o2 = ((size_t)b * N + sg) * 256;
        ekv[o2 + d]       = ek * v[off];
        ekv[o2 + 128 + d] = ek;
    }
}

// ---------------------------------------------------------------------------
// Fused AAFM attention + LN1 — r14 structure (single prefetch, acc[16]
// split-s, all-wave epilogue). Unchanged.
// ---------------------------------------------------------------------------
__global__ __launch_bounds__(256) void attn_kernel(
    const float* __restrict__ pdist, const float* __restrict__ mask,
    const float* __restrict__ ekv, const float* __restrict__ q,
    const float* xres, const float* __restrict__ g, const float* __restrict__ be,
    const int* __restrict__ nnum, const float* __restrict__ alphaAttn, int layer,
    float* outp)
{
    __shared__ float ew[16][516];
    __shared__ float red16[16][16];
    __shared__ float rmax[16];
    const int d0  = blockIdx.x;          // XCD-aware bijective swizzle
    const int xcd = d0 & 7;
    const int idx = d0 >> 3;
    const int tl  = idx & 31;
    const int b   = (idx >> 5) * 8 + xcd;
    const int t0  = tl * 16;
    const int tid = threadIdx.x;
    const float la = -log2f((float)nnum[b]) * alphaAttn[layer];
    const float* pd = pdist + ((size_t)b * N + t0) * N;
    const float* mk = mask + (size_t)b * N;

    #pragma unroll
    for (int i = 0; i < 8; ++i) {
        int f = tid + i * 256;
        int r = f >> 7, s4 = (f & 127) * 4;
        float4 p = *(const float4*)&pd[(size_t)r * N + s4];
        float4 m = *(const float4*)&mk[s4];
        float4 w;
        w.x = fmaf(la, p.x, m.x); w.y = fmaf(la, p.y, m.y);
        w.z = fmaf(la, p.z, m.z); w.w = fmaf(la, p.w, m.w);
        *(float4*)&ew[r][s4] = w;
    }
    __syncthreads();
    {   // row max: stride-16 interleave -> <=2-way banks
        int r = tid >> 4, j0 = tid & 15;
        float m = -3.4e38f;
        #pragma unroll 8
        for (int j = 0; j < 32; ++j) m = fmaxf(m, ew[r][j0 + 16 * j]);
        red16[r][j0] = m;
    }
    __syncthreads();
    if (tid < 16) {
        float m = red16[tid][0];
        #pragma unroll
        for (int j = 1; j < 16; ++j) m = fmaxf(m, red16[tid][j]);
        rmax[tid] = m;
    }
    __syncthreads();
    #pragma unroll
    for (int i = 0; i < 8; ++i) {
        int f = tid + i * 256;
        int r = f >> 7, s4 = (f & 127) * 4;
        float m = rmax[r];
        float4 w = *(float4*)&ew[r][s4];
        w.x = expf(w.x - m); w.y = expf(w.y - m);
        w.z = expf(w.z - m); w.w = expf(w.w - m);
        *(float4*)&ew[r][s4] = w;
    }
    __syncthreads();

    // ----- split-s partial [num|den] -----
    const int lane = tid & 63;
    const int wv   = tid >> 6;
    const int c4   = lane * 4;
    float4 acc[16];
    #pragma unroll
    for (int r = 0; r < 16; ++r) acc[r] = make_float4(0.f, 0.f, 0.f, 0.f);
    const float* ep = ekv + (size_t)b * N * 256 + c4;
    const int sb = wv * 128;
    float4 e0 = *(const float4*)&ep[(size_t)(sb + 0) * 256];
    float4 e1 = *(const float4*)&ep[(size_t)(sb + 1) * 256];
    float4 e2 = *(const float4*)&ep[(size_t)(sb + 2) * 256];
    float4 e3 = *(const float4*)&ep[(size_t)(sb + 3) * 256];
    for (int it = 0; it < 32; ++it) {
        const int s = sb + it * 4;
        float4 f0 = e0, f1 = e1, f2 = e2, f3 = e3;
        int sn = (it < 31) ? (s + 4) : s;       // uniform clamp
        e0 = *(const float4*)&ep[(size_t)(sn + 0) * 256];
        e1 = *(const float4*)&ep[(size_t)(sn + 1) * 256];
        e2 = *(const float4*)&ep[(size_t)(sn + 2) * 256];
        e3 = *(const float4*)&ep[(size_t)(sn + 3) * 256];
        #pragma unroll
        for (int r = 0; r < 16; ++r) {
            float4 a = *(float4*)&ew[r][s];
            acc[r].x = fmaf(a.x, f0.x, acc[r].x); acc[r].x = fmaf(a.y, f1.x, acc[r].x);
            acc[r].x = fmaf(a.z, f2.x, acc[r].x); acc[r].x = fmaf(a.w, f3.x, acc[r].x);
            acc[r].y = fmaf(a.x, f0.y, acc[r].y); acc[r].y = fmaf(a.y, f1.y, acc[r].y);
            acc[r].y = fmaf(a.z, f2.y, acc[r].y); acc[r].y = fmaf(a.w, f3.y, acc[r].y);
            acc[r].z = fmaf(a.x, f0.z, acc[r].z); acc[r].z = fmaf(a.y, f1.z, acc[r].z);
            acc[r].z = fmaf(a.z, f2.z, acc[r].z); acc[r].z = fmaf(a.w, f3.z, acc[r].z);
            acc[r].w = fmaf(a.x, f0.w, acc[r].w); acc[r].w = fmaf(a.y, f1.w, acc[r].w);
            acc[r].w = fmaf(a.z, f2.w, acc[r].w); acc[r].w = fmaf(a.w, f3.w, acc[r].w);
        }
    }

    // ----- cross-wave reduction: (w0 + w1) + (w2 + w3) -----
    float* red = &ew[0][0];
    __syncthreads();
    if (wv == 1) {
        #pragma unroll
        for (int r = 0; r < 16; ++r) *(float4*)&red[r * 256 + c4] = acc[r];
    }
    if (wv == 3) {
        #pragma unroll
        for (int r = 0; r < 16; ++r) *(float4*)&red[4096 + r * 256 + c4] = acc[r];
    }
    __syncthreads();
    if (wv == 0) {
        #pragma unroll
        for (int r = 0; r < 16; ++r) { float4 t = *(float4*)&red[r * 256 + c4]; F4ADD(acc[r], t); }
    }
    if (wv == 2) {
        #pragma unroll
        for (int r = 0; r < 16; ++r) { float4 t = *(float4*)&red[4096 + r * 256 + c4]; F4ADD(acc[r], t); }
    }
    __syncthreads();
    if (wv == 2) {
        #pragma unroll
        for (int r = 0; r < 16; ++r) *(float4*)&red[r * 256 + c4] = acc[r];
    }
    __syncthreads();
    if (wv == 0) {
        #pragma unroll
        for (int r = 0; r < 16; ++r) {
            float4 t = *(float4*)&red[r * 256 + c4];
            F4ADD(acc[r], t);
            *(float4*)&red[r * 256 + c4] = acc[r];   // publish final
        }
    }
    __syncthreads();

    // ----- all-wave epilogue: wave wv owns rows wv*4..wv*4+3 -----
    if (lane < 32) {
        const int c = lane * 4;
        #pragma unroll
        for (int i = 0; i < 4; ++i) {
            int row = wv * 4 + i;
            float4 nu = *(float4*)&red[row * 256 + c];
            float4 de = *(float4*)&red[row * 256 + 128 + c];
            size_t off = ((size_t)b * N + t0 + row) * D + c;
            float4 qq = *(const float4*)&q[off];
            float4 av;
            av.x = sigmoidf_(qq.x) * nu.x / de.x;
            av.y = sigmoidf_(qq.y) * nu.y / de.y;
            av.z = sigmoidf_(qq.z) * nu.z / de.z;
            av.w = sigmoidf_(qq.w) * nu.w / de.w;
            float4 xv = *(const float4*)&xres[off];
            float y0 = xv.x + av.x, y1 = xv.y + av.y;
            float y2 = xv.z + av.z, y3 = xv.w + av.w;
            float s = ((y0 + y1) + y2) + y3;
            #pragma unroll
            for (int mm = 16; mm > 0; mm >>= 1) s += __shfl_xor(s, mm);
            float mean = s * (1.f / 128.f);
            float d0_ = y0 - mean, d1_ = y1 - mean, d2_ = y2 - mean, d3_ = y3 - mean;
            float ss = ((d0_ * d0_ + d1_ * d1_) + d2_ * d2_) + d3_ * d3_;
            #pragma unroll
            for (int mm = 16; mm > 0; mm >>= 1) ss += __shfl_xor(ss, mm);
            float rs = rsqrtf(ss * (1.f / 128.f) + 1e-5f);
            float4 ov;
            ov.x = d0_ * rs * g[c]     + be[c];
            ov.y = d1_ * rs * g[c + 1] + be[c + 1];
            ov.z = d2_ * rs * g[c + 2] + be[c + 2];
            ov.w = d3_ * rs * g[c + 3] + be[c + 3];
            *(float4*)&outp[off] = ov;
        }
    }
}

// ---------------------------------------------------------------------------
// Final head (r8-validated): f64 score dot, XLA-f32 FastTanh, f32 softmax,
// first-occurrence argmax over p.
// ---------------------------------------------------------------------------
__global__ __launch_bounds__(512) void k_final(
    const float* __restrict__ x, const float* __restrict__ pdist,
    const float* __restrict__ mask, const int* __restrict__ nnum,
    const int* __restrict__ nidx, const float* __restrict__ aCom,
    float* __restrict__ out)
{
    __shared__ float  sc[512];
    __shared__ float  ee[512];
    __shared__ double qo[128];
    int b = blockIdx.x, tid = threadIdx.x;
    const float* xb = x + (size_t)b * N * D;
    if (tid < 128) qo[tid] = (double)xb[tid] + (double)xb[128 + tid];
    __syncthreads();
    if (tid < NNB) {
        const float* xr = xb + (size_t)(2 + tid) * 128;
        double s = 0.0;
        for (int dd = 0; dd < 128; ++dd) s += qo[dd] * (double)xr[dd];
        double lg = -log2((double)nnum[b]);
        s = s / 11.313708498984761
          + (double)aCom[0] * lg * (double)pdist[((size_t)b * 512 + 1) * 512 + 2 + tid];
        float t = xla_fast_tanh((float)s);
        sc[tid] = __fadd_rn(__fmul_rn(10.0f, t),
                            mask[(size_t)b * 512 + 2 + tid]);
    }
    __syncthreads();
    if (tid == 0) {
        float m = -3.4e38f;
        for (int n2 = 0; n2 < NNB; ++n2) m = fmaxf(m, sc[n2]);
        float S = 0.f;
        for (int n2 = 0; n2 < NNB; ++n2) {
            float e = expf(__fadd_rn(sc[n2], -m));
            ee[n2] = e;
            S = __fadd_rn(S, e);
        }
        float bestp = -1.f; int sel = 0;
        for (int n2 = 0; n2 < NNB; ++n2) {
            float p = ee[n2] / S;
            if (p > bestp) { bestp = p; sel = n2; }
        }
        out[b]     = (float)nidx[(size_t)b * NNB + sel];
        out[B + b] = bestp;
    }
}

// ---------------------------------------------------------------------------
extern "C" void kernel_launch(void* const* d_in, const int* in_sizes, int n_in,
                              void* d_out, int out_size, void* d_ws, size_t ws_size,
                              hipStream_t stream)
{
    const float* xy     = (const float*)d_in[0];
    const float* load   = (const float*)d_in[1];
    const float* demand = (const float*)d_in[2];
    const float* mask   = (const float*)d_in[3];
    const float* pdist  = (const float*)d_in[4];
    const int*   nnum   = (const int*)d_in[5];
    const int*   nidx   = (const int*)d_in[6];
    const float* embW   = (const float*)d_in[7];
    const float* embb   = (const float*)d_in[8];
    const float* wload  = (const float*)d_in[9];
    const float* wdem   = (const float*)d_in[10];
    const float* Wqf    = (const float*)d_in[11];
    const float* Wql    = (const float*)d_in[12];
    const float* aCom   = (const float*)d_in[13];
    const float* Wq     = (const float*)d_in[14];
    const float* Wk     = (const float*)d_in[15];
    const float* Wv     = (const float*)d_in[16];
    const float* aAttn  = (const float*)d_in[17];
    const float* ln1g   = (const float*)d_in[18];
    const float* ln1b   = (const float*)d_in[19];
    const float* ln2g   = (const float*)d_in[20];
    const float* ln2b   = (const float*)d_in[21];
    const float* fW1    = (const float*)d_in[22];
    const float* fb1    = (const float*)d_in[23];
    const float* fW2    = (const float*)d_in[24];
    const float* fb2    = (const float*)d_in[25];
    float* out = (float*)d_out;

    // Workspace: 6*SZ + part (192 MB + 0.5 MB; ws >= 224 MiB per r6 sentinel).
    float* ws = (float*)d_ws;
    const size_t SZ = (size_t)B * N * D;      // 8388608 floats
    float* xbuf  = ws;                        // slot 0 (residual stream)
    float* qbuf  = ws + SZ;                   // slot 1
    float* kbuf  = ws + 2 * SZ;               // slot 2 (raw k; free post-ekv)
    float* vbuf  = ws + 3 * SZ;               // slot 3 (free post-ekv)
    float* ekv   = ws + 4 * SZ;               // slots 4-5 (free post-attn)
    float* part  = ws + 6 * SZ;               // 1024*128 floats (0.5 MB)
    float* bigh  = kbuf;                      // ff hidden full-M: slots 2-5

    build_x_kernel<<<B * N, 128, 0, stream>>>(xy, load, demand, mask, embW, embb,
                                              wload, wdem, Wqf, Wql, xbuf);
    const int M = B * N;                      // 65536
    for (int l = 0; l < NL; ++l) {
        // fused QKV: grid (M/64, 3)
        gemm_f32<false, false, 0><<<dim3(M / 64, 3), 256, 0, stream>>>(
            xbuf, Wq + (size_t)l * D * D, Wk + (size_t)l * D * D, Wv + (size_t)l * D * D,
            nullptr, qbuf, kbuf, vbuf, nullptr, nullptr, nullptr, M, D, D);
        colmax_part<<<B * 8, 128, 0, stream>>>(kbuf, part);
        ekv_build<<<B * 8, 128, 0, stream>>>(kbuf, vbuf, part, ekv);
        // attention + fused LN1 (writes xbuf in place)
        attn_kernel<<<B * 32, 256, 0, stream>>>(
            pdist, mask, ekv, qbuf, xbuf, ln1g + l * D, ln1b + l * D,
            nnum, aAttn, l, xbuf);
        // FF at full M (bigh spans slots 2-5)
        gemm_f32<true, true, 0><<<dim3(M / 64, FFH / 128), 256, 0, stream>>>(
            xbuf, fW1 + (size_t)l * D * FFH, nullptr, nullptr, fb1 + l * FFH,
            bigh, nullptr, nullptr, nullptr, nullptr, nullptr, M, D, FFH);
        // FF2 + fused LN2 (writes xbuf in place, resid = xbuf)
        gemm_f32<true, false, 1><<<dim3(M / 64, 1), 256, 0, stream>>>(
            bigh, fW2 + (size_t)l * FFH * D, nullptr, nullptr, fb2 + l * D,
            xbuf, nullptr, nullptr, xbuf, ln2g + l * D, ln2b + l * D, M, FFH, D);
    }
    k_final<<<B, 512, 0, stream>>>(xbuf, pdist, mask, nnum, nidx, aCom, out);
}